// Round 1
// baseline (64.582 us; speedup 1.0000x reference)
//
#include <hip/hip_runtime.h>
#include <cstddef>

typedef __attribute__((ext_vector_type(8))) short bf16x8;
typedef __attribute__((ext_vector_type(4))) short short4v;
typedef __attribute__((ext_vector_type(16))) float f32x16;

__device__ __forceinline__ unsigned short f2bf(float f) {
  union { float f; unsigned u; } v; v.f = f;
  unsigned r = v.u + 0x7FFFu + ((v.u >> 16) & 1u);  // round-to-nearest-even
  return (unsigned short)(r >> 16);
}

// ---------------- stage 1: global average pool ----------------
// grid = B*INP = 4096 blocks, 256 threads; each block reduces one [64x64] plane
__global__ __launch_bounds__(256) void gap_kernel(const float* __restrict__ x,
                                                  float* __restrict__ gap) {
  const int bid = blockIdx.x;
  const float* p = x + (size_t)bid * 4096;
  const int t = threadIdx.x;
  float s = 0.f;
#pragma unroll
  for (int j = 0; j < 4; ++j) {
    const float4 v = *reinterpret_cast<const float4*>(p + j * 1024 + t * 4);
    s += v.x + v.y + v.z + v.w;
  }
#pragma unroll
  for (int off = 32; off > 0; off >>= 1) s += __shfl_down(s, off, 64);
  __shared__ float wsum[4];
  if ((t & 63) == 0) wsum[t >> 6] = s;
  __syncthreads();
  if (t == 0) gap[bid] = (wsum[0] + wsum[1] + wsum[2] + wsum[3]) * (1.f / 4096.f);
}

// ---------------- stage 2: glgf weight/gate generation + MFMA-order pack ----
// grid = B*CGROUP = 128 blocks ((b,g)), 256 threads.
// Packs W as bf16 in A-fragment order: wpack[(bg*18+kk)*512 + lane*8 + e]
// with oc = lane%32, k' = kk*16 + 8*(lane/32) + e, k' = (ky*3+kx)*32 + ic.
__global__ __launch_bounds__(256) void glgf_pack(
    const float* __restrict__ gap,
    const float* __restrict__ w1l, const float* __restrict__ w1g1,
    const float* __restrict__ w1g2, const float* __restrict__ w2l,
    const float* __restrict__ w2g,
    const float* __restrict__ v1l, const float* __restrict__ v1g1,
    const float* __restrict__ v1g2, const float* __restrict__ v2l,
    const float* __restrict__ v2g,
    unsigned short* __restrict__ wpack, float* __restrict__ gate) {
  __shared__ float gapL[256];
  __shared__ float t1L[16];
  __shared__ float hL[256];
  __shared__ float red[256];
  const int bg = blockIdx.x;
  const int g = bg & 7, b = bg >> 3;
  const int c = threadIdx.x;
  gapL[c] = gap[b * 256 + c];
  __syncthreads();

  const int gbase = c & ~15;
  // generator 1: h1 = sigmoid(local + glob)
  float local1 = 0.f;
#pragma unroll
  for (int i = 0; i < 16; ++i) local1 += gapL[gbase + i] * w1l[c * 16 + i];
  if (c < 16) {
    float t = 0.f;
#pragma unroll
    for (int i = 0; i < 16; ++i) t += gapL[c * 16 + i] * w1g1[c * 16 + i];
    t1L[c] = t;
  }
  __syncthreads();
  float glob1 = 0.f;
#pragma unroll
  for (int gg = 0; gg < 16; ++gg) glob1 += t1L[gg] * w1g2[c * 16 + gg];
  const float h1 = 1.f / (1.f + expf(-(local1 + glob1)));
  hL[c] = h1;
  red[c] = h1 * w2g[c];
  __syncthreads();
  for (int s = 128; s > 0; s >>= 1) {
    if (c < s) red[c] += red[c + s];
    __syncthreads();
  }
  const float glob2 = red[0];

  // pack this (b,g)'s W slice: 18 K-steps * 512 lane-elems = 9216 bf16
  unsigned short* wpo = wpack + (size_t)bg * 9216;
  for (int it = 0; it < 36; ++it) {
    const int idx = it * 256 + c;
    const int kk = idx >> 9;
    const int rem = idx & 511;
    const int l = rem >> 3, e = rem & 7;
    const int oc = l & 31, hi = l >> 5;
    const int ic = ((kk & 1) << 4) + hi * 8 + e;  // k' % 32
    const int sp = kk >> 1;                       // (ky*3+kx) = k'/32
    const int o = (g << 5) + oc;
    const float wv = hL[o] * w2l[o * 288 + ic * 9 + sp] + glob2;
    wpo[idx] = f2bf(wv);
  }

  // generator 2 (gate), only needed once per b
  if (g == 0) {
    __syncthreads();
    float local2 = 0.f;
#pragma unroll
    for (int i = 0; i < 16; ++i) local2 += gapL[gbase + i] * v1l[c * 16 + i];
    if (c < 16) {
      float t = 0.f;
#pragma unroll
      for (int i = 0; i < 16; ++i) t += gapL[c * 16 + i] * v1g1[c * 16 + i];
      t1L[c] = t;
    }
    __syncthreads();
    float glob1b = 0.f;
#pragma unroll
    for (int gg = 0; gg < 16; ++gg) glob1b += t1L[gg] * v1g2[c * 16 + gg];
    const float h2 = 1.f / (1.f + expf(-(local2 + glob1b)));
    red[c] = h2 * v2g[c];
    __syncthreads();
    for (int s = 128; s > 0; s >>= 1) {
      if (c < s) red[c] += red[c + s];
      __syncthreads();
    }
    gate[b * 256 + c] = h2 * v2l[c] + red[0];
  }
}

// ---------------- stage 3: dynamic grouped conv via implicit GEMM + MFMA ----
// grid = B*CGROUP*32 = 4096 blocks ((b,g,row-pair)), 256 threads = 4 waves.
// Each wave: one 32(oc) x 32(spatial) MFMA tile; K = 288 = 18 steps of 16.
#define CELL 40  // padded channel-last cell (32 ic -> 40): 80B stride, 16B-aligned
__global__ __launch_bounds__(256) void conv_kernel(
    const float* __restrict__ x, const unsigned short* __restrict__ wpack,
    const float* __restrict__ gate, float* __restrict__ out) {
  __shared__ unsigned short patch[4 * 66 * CELL];  // 21120 B, channel-last bf16
  const int bid = blockIdx.x;
  const int tileY = bid & 31;
  const int g = (bid >> 5) & 7;
  const int b = bid >> 8;
  const int r0 = tileY * 2;
  const int tid = threadIdx.x;

  // stage input patch: rows r0-1..r0+2, cols -1..64, 32 channels, channel-last
  const float* xg = x + (size_t)(b * 256 + g * 32) * 4096;
  for (int idx = tid; idx < 4 * 8 * 66; idx += 256) {
    const int col = idx % 66;
    const int rest = idx / 66;
    const int icq = rest & 7;
    const int row = rest >> 3;
    const int gy = r0 - 1 + row;
    const int gx = col - 1;
    const bool ok = (gy >= 0) && (gy < 64) && (gx >= 0) && (gx < 64);
    short4v sv;
#pragma unroll
    for (int j = 0; j < 4; ++j) {
      const float v = ok ? xg[(size_t)(icq * 4 + j) * 4096 + gy * 64 + gx] : 0.f;
      sv[j] = (short)f2bf(v);
    }
    *reinterpret_cast<short4v*>(&patch[(row * 66 + col) * CELL + icq * 4]) = sv;
  }
  __syncthreads();

  const int lane = tid & 63, wave = tid >> 6;
  const int n = lane & 31, hi = lane >> 5;
  const int wr = wave >> 1, wc = wave & 1;  // wave -> (row offset, col half)

  f32x16 acc;
#pragma unroll
  for (int i = 0; i < 16; ++i) acc[i] = 0.f;

  const unsigned short* wp =
      wpack + (size_t)((b * 8 + g) * 18) * 512 + lane * 8;
#pragma unroll
  for (int kk = 0; kk < 18; ++kk) {
    const bf16x8 afrag = *reinterpret_cast<const bf16x8*>(wp + kk * 512);
    const int sp = kk >> 1;
    const int ky = sp / 3, kx = sp % 3;
    const int addr = ((wr + ky) * 66 + (wc * 32 + n + kx)) * CELL +
                     ((kk & 1) << 4) + hi * 8;
    const bf16x8 bfrag = *reinterpret_cast<const bf16x8*>(&patch[addr]);
    acc = __builtin_amdgcn_mfma_f32_32x32x16_bf16(afrag, bfrag, acc, 0, 0, 0);
  }

  // epilogue: apply per-channel gate, store fp32
  const int px = wc * 32 + n, py = r0 + wr;
  float* ob = out + (size_t)(b * 256 + g * 32) * 4096 + py * 64 + px;
  const float* gb = gate + b * 256 + g * 32;
#pragma unroll
  for (int r = 0; r < 16; ++r) {
    const int row = (r & 3) + ((r >> 2) << 3) + (hi << 2);
    ob[(size_t)row * 4096] = acc[r] * gb[row];
  }
}

extern "C" void kernel_launch(void* const* d_in, const int* in_sizes, int n_in,
                              void* d_out, int out_size, void* d_ws,
                              size_t ws_size, hipStream_t stream) {
  const float* x    = (const float*)d_in[0];
  const float* w1l  = (const float*)d_in[1];
  const float* w1g1 = (const float*)d_in[2];
  const float* w1g2 = (const float*)d_in[3];
  const float* w2l  = (const float*)d_in[4];
  const float* w2g  = (const float*)d_in[5];
  const float* v1l  = (const float*)d_in[6];
  const float* v1g1 = (const float*)d_in[7];
  const float* v1g2 = (const float*)d_in[8];
  const float* v2l  = (const float*)d_in[9];
  const float* v2g  = (const float*)d_in[10];
  float* out = (float*)d_out;

  float* gap = (float*)d_ws;                              // 4096 f32
  float* gate = gap + 4096;                               // 4096 f32
  unsigned short* wpack = (unsigned short*)(gate + 4096); // 1,179,648 bf16

  gap_kernel<<<4096, 256, 0, stream>>>(x, gap);
  glgf_pack<<<128, 256, 0, stream>>>(gap, w1l, w1g1, w1g2, w2l, w2g,
                                     v1l, v1g1, v1g2, v2l, v2g, wpack, gate);
  conv_kernel<<<4096, 256, 0, stream>>>(x, wpack, gate, out);
}

// Round 2
// 63.812 us; speedup vs baseline: 1.0121x; 1.0121x over previous
//
#include <hip/hip_runtime.h>
#include <cstddef>

typedef __attribute__((ext_vector_type(8))) short bf16x8;
typedef __attribute__((ext_vector_type(4))) unsigned short ushort4v;
typedef __attribute__((ext_vector_type(8))) unsigned short ushort8v;
typedef __attribute__((ext_vector_type(16))) float f32x16;

__device__ __forceinline__ unsigned short f2bf(float f) {
  union { float f; unsigned u; } v; v.f = f;
  unsigned r = v.u + 0x7FFFu + ((v.u >> 16) & 1u);  // round-to-nearest-even
  return (unsigned short)(r >> 16);
}

// ---------------- stage 1: x -> bf16 channel-last (zero-padded) + gap partials
// grid = B*CGROUP*32 = 4096 blocks ((b,g,row-pair)), 256 threads.
// xt layout: [b][g][66 row][66 col][32 ic] bf16, 1-px zero halo.
#define PADC 132
__global__ __launch_bounds__(256) void prep_kernel(
    const float* __restrict__ x, unsigned short* __restrict__ xt,
    float* __restrict__ partials) {
  __shared__ unsigned short cm[32 * PADC];  // channel-major bf16: [ic][128 px]
  __shared__ float sred[32][32];
  const int bid = blockIdx.x;
  const int yp = bid & 31, g = (bid >> 5) & 7, b = bid >> 8;
  const int y0 = yp * 2;
  const int tid = threadIdx.x;
  const float* xg = x + (size_t)(b * 256 + g * 32) * 4096;

  float csum[4];
#pragma unroll
  for (int j = 0; j < 4; ++j) {
    const int idx = tid + 256 * j;
    const int ic = idx >> 5;  // 0..31
    const int r = idx & 31;
    const int ry = r >> 4, gx4 = (r & 15) * 4;
    const float4 v = *reinterpret_cast<const float4*>(
        xg + (size_t)ic * 4096 + (y0 + ry) * 64 + gx4);
    csum[j] = v.x + v.y + v.z + v.w;
    ushort4v s;
    s[0] = f2bf(v.x); s[1] = f2bf(v.y); s[2] = f2bf(v.z); s[3] = f2bf(v.w);
    *reinterpret_cast<ushort4v*>(&cm[ic * PADC + ry * 64 + gx4]) = s;
  }
#pragma unroll
  for (int j = 0; j < 4; ++j) {
    const int ic = (tid >> 5) + 8 * j;
    sred[ic][tid & 31] = csum[j];
  }
  __syncthreads();

  // per-channel partial sums for gap (fp32, pre-conversion values)
  if (tid < 32) {
    float s = 0.f;
#pragma unroll
    for (int i = 0; i < 32; ++i) s += sred[tid][i];
    partials[(size_t)(b * 256 + g * 32 + tid) * 32 + yp] = s;
  }

  // transposed store: 2 rows x 64 cols x 32 ic -> xt interior
  const size_t xtb = (size_t)(b * 8 + g) * (66 * 66 * 32);
#pragma unroll
  for (int jj = 0; jj < 2; ++jj) {
    const int o = tid + 256 * jj;  // 0..511
    const int px = o >> 2, icq = o & 3;
    const int ry = px >> 6, gx = px & 63;
    ushort8v t;
#pragma unroll
    for (int c = 0; c < 8; ++c) t[c] = cm[(icq * 8 + c) * PADC + px];
    *reinterpret_cast<ushort8v*>(
        &xt[xtb + ((size_t)(y0 + ry + 1) * 66 + (gx + 1)) * 32 + icq * 8]) = t;
  }

  // zero halo: side columns for this block's two rows
  const ushort8v z = {0, 0, 0, 0, 0, 0, 0, 0};
  if (tid < 16) {
    const int rr = tid >> 3;
    const int side = (tid >> 2) & 1;
    const int icq = tid & 3;
    const int col = side * 65;
    *reinterpret_cast<ushort8v*>(
        &xt[xtb + ((size_t)(y0 + rr + 1) * 66 + col) * 32 + icq * 8]) = z;
  }
  if (yp == 0 || yp == 31) {
    const int row = (yp == 0) ? 0 : 65;
    for (int o = tid; o < 66 * 4; o += 256) {
      const int col = o >> 2, icq = o & 3;
      *reinterpret_cast<ushort8v*>(
          &xt[xtb + ((size_t)row * 66 + col) * 32 + icq * 8]) = z;
    }
  }
}

// ---------------- stage 2: glgf weight/gate generation + MFMA-order pack ----
// grid = B*CGROUP = 128 blocks ((b,g)), 256 threads.
// wpack A-fragment order: wpack[(bg*18+kk)*512 + lane*8 + e]
// oc = lane%32, k' = kk*16 + 8*(lane/32) + e, k' = (ky*3+kx)*32 + ic.
__global__ __launch_bounds__(256) void glgf_pack(
    const float* __restrict__ partials,
    const float* __restrict__ w1l, const float* __restrict__ w1g1,
    const float* __restrict__ w1g2, const float* __restrict__ w2l,
    const float* __restrict__ w2g,
    const float* __restrict__ v1l, const float* __restrict__ v1g1,
    const float* __restrict__ v1g2, const float* __restrict__ v2l,
    const float* __restrict__ v2g,
    unsigned short* __restrict__ wpack, float* __restrict__ gate) {
  __shared__ float gapL[256];
  __shared__ float t1L[16];
  __shared__ float hL[256];
  __shared__ float red[256];
  const int bg = blockIdx.x;
  const int g = bg & 7, b = bg >> 3;
  const int c = threadIdx.x;
  {
    float s = 0.f;
    const float* pp = partials + (size_t)(b * 256 + c) * 32;
#pragma unroll
    for (int i = 0; i < 32; ++i) s += pp[i];
    gapL[c] = s * (1.f / 4096.f);
  }
  __syncthreads();

  const int gbase = c & ~15;
  float local1 = 0.f;
#pragma unroll
  for (int i = 0; i < 16; ++i) local1 += gapL[gbase + i] * w1l[c * 16 + i];
  if (c < 16) {
    float t = 0.f;
#pragma unroll
    for (int i = 0; i < 16; ++i) t += gapL[c * 16 + i] * w1g1[c * 16 + i];
    t1L[c] = t;
  }
  __syncthreads();
  float glob1 = 0.f;
#pragma unroll
  for (int gg = 0; gg < 16; ++gg) glob1 += t1L[gg] * w1g2[c * 16 + gg];
  const float h1 = 1.f / (1.f + expf(-(local1 + glob1)));
  hL[c] = h1;
  red[c] = h1 * w2g[c];
  __syncthreads();
  for (int s = 128; s > 0; s >>= 1) {
    if (c < s) red[c] += red[c + s];
    __syncthreads();
  }
  const float glob2 = red[0];

  unsigned short* wpo = wpack + (size_t)bg * 9216;
  for (int it = 0; it < 36; ++it) {
    const int idx = it * 256 + c;
    const int kk = idx >> 9;
    const int rem = idx & 511;
    const int l = rem >> 3, e = rem & 7;
    const int oc = l & 31, hi = l >> 5;
    const int ic = ((kk & 1) << 4) + hi * 8 + e;
    const int sp = kk >> 1;
    const int o = (g << 5) + oc;
    const float wv = hL[o] * w2l[o * 288 + ic * 9 + sp] + glob2;
    wpo[idx] = f2bf(wv);
  }

  if (g == 0) {
    __syncthreads();
    float local2 = 0.f;
#pragma unroll
    for (int i = 0; i < 16; ++i) local2 += gapL[gbase + i] * v1l[c * 16 + i];
    if (c < 16) {
      float t = 0.f;
#pragma unroll
      for (int i = 0; i < 16; ++i) t += gapL[c * 16 + i] * v1g1[c * 16 + i];
      t1L[c] = t;
    }
    __syncthreads();
    float glob1b = 0.f;
#pragma unroll
    for (int gg = 0; gg < 16; ++gg) glob1b += t1L[gg] * v1g2[c * 16 + gg];
    const float h2 = 1.f / (1.f + expf(-(local2 + glob1b)));
    red[c] = h2 * v2g[c];
    __syncthreads();
    for (int s = 128; s > 0; s >>= 1) {
      if (c < s) red[c] += red[c + s];
      __syncthreads();
    }
    gate[b * 256 + c] = h2 * v2l[c] + red[0];
  }
}

// ---------------- stage 3: LDS-free implicit-GEMM conv, MFMA from global ----
// grid = 4096 blocks ((b,g,row-pair)), 256 threads = 4 waves.
// Each wave: 32(oc) x 32(px) tile, one output row, K = 288 = 18 steps.
__global__ __launch_bounds__(256) void conv_kernel(
    const unsigned short* __restrict__ xt,
    const unsigned short* __restrict__ wpack,
    const float* __restrict__ gate, float* __restrict__ out) {
  // XCD-chunked swizzle (4096 % 8 == 0 -> bijective)
  const int wid = ((blockIdx.x & 7) << 9) | (blockIdx.x >> 3);
  const int yp = wid & 31, g = (wid >> 5) & 7, b = wid >> 8;
  const int tid = threadIdx.x;
  const int lane = tid & 63, wave = tid >> 6;
  const int n = lane & 31, hi = lane >> 5;
  const int wr = wave >> 1, wc = wave & 1;
  const int y = yp * 2 + wr;
  const int px = wc * 32 + n;

  const unsigned short* xb = xt + (size_t)(b * 8 + g) * (66 * 66 * 32) +
                             ((size_t)y * 66 + px) * 32 + hi * 8;
  const unsigned short* wp =
      wpack + (size_t)((b * 8 + g) * 18) * 512 + lane * 8;

  f32x16 acc;
#pragma unroll
  for (int i = 0; i < 16; ++i) acc[i] = 0.f;

#pragma unroll
  for (int kk = 0; kk < 18; ++kk) {
    const int sp = kk >> 1;
    const int ky = sp / 3, kx = sp % 3;
    const bf16x8 afrag = *reinterpret_cast<const bf16x8*>(wp + kk * 512);
    const bf16x8 bfrag = *reinterpret_cast<const bf16x8*>(
        xb + (ky * 66 + kx) * 32 + (kk & 1) * 16);
    acc = __builtin_amdgcn_mfma_f32_32x32x16_bf16(afrag, bfrag, acc, 0, 0, 0);
  }

  float* ob = out + (size_t)(b * 256 + g * 32) * 4096 + y * 64 + px;
  const float* gb = gate + b * 256 + g * 32;
#pragma unroll
  for (int r = 0; r < 16; ++r) {
    const int row = (r & 3) + ((r >> 2) << 3) + (hi << 2);
    ob[(size_t)row * 4096] = acc[r] * gb[row];
  }
}

extern "C" void kernel_launch(void* const* d_in, const int* in_sizes, int n_in,
                              void* d_out, int out_size, void* d_ws,
                              size_t ws_size, hipStream_t stream) {
  const float* x    = (const float*)d_in[0];
  const float* w1l  = (const float*)d_in[1];
  const float* w1g1 = (const float*)d_in[2];
  const float* w1g2 = (const float*)d_in[3];
  const float* w2l  = (const float*)d_in[4];
  const float* w2g  = (const float*)d_in[5];
  const float* v1l  = (const float*)d_in[6];
  const float* v1g1 = (const float*)d_in[7];
  const float* v1g2 = (const float*)d_in[8];
  const float* v2l  = (const float*)d_in[9];
  const float* v2g  = (const float*)d_in[10];
  float* out = (float*)d_out;

  unsigned short* xt = (unsigned short*)d_ws;          // 17,842,176 bf16
  unsigned short* wpack = xt + 17842176;               // 1,179,648 bf16
  float* partials = (float*)(wpack + 1179648);         // 131,072 f32
  float* gate = partials + 131072;                     // 4,096 f32

  prep_kernel<<<4096, 256, 0, stream>>>(x, xt, partials);
  glgf_pack<<<128, 256, 0, stream>>>(partials, w1l, w1g1, w1g2, w2l, w2g,
                                     v1l, v1g1, v1g2, v2l, v2g, wpack, gate);
  conv_kernel<<<4096, 256, 0, stream>>>(xt, wpack, gate, out);
}